// Round 11
// baseline (200.379 us; speedup 1.0000x reference)
//
#include <hip/hip_runtime.h>
#include <math.h>

#define NJ 17
#define CPJ 8
#define NBATCH 8
#define NSP 1728
#define NC 136
#define WA_OFF 1880064  // element offset of bf16 A copy inside bf16 ws region
#define SST 148         // epilogue scratch stride (floats)

typedef short short8 __attribute__((ext_vector_type(8)));
typedef float f32x4 __attribute__((ext_vector_type(4)));

__device__ __forceinline__ short f2bf(float f) {
  unsigned u = __builtin_bit_cast(unsigned, f);
  u += 0x7FFFu + ((u >> 16) & 1u);   // RNE
  return (short)(u >> 16);
}

__device__ const int d_CA[16] = {0,1,2,5,4,3,6,7,8,9,8,11,10,8,13,14};
__device__ const int d_CB[16] = {1,2,6,4,3,6,7,8,16,16,12,12,11,13,14,15};
__device__ const int d_Gcnt[17] = {1,2,2,2,2,1,3,2,4,1,1,2,2,2,2,1,2};
__device__ const int d_Gj1[17][4] = {
  {1,0,0,0},{0,2,0,0},{1,6,0,0},{4,6,0,0},{5,3,0,0},{4,0,0,0},{2,3,7,0},{6,8,0,0},
  {7,16,12,13},{16,0,0,0},{11,0,0,0},{12,10,0,0},{8,11,0,0},{8,14,0,0},{13,15,0,0},
  {14,0,0,0},{8,9,0,0}};
__device__ const int d_Glim[17][4] = {
  {0,0,0,0},{0,1,0,0},{1,2,0,0},{4,5,0,0},{3,4,0,0},{3,0,0,0},{2,5,6,0},{6,7,0,0},
  {7,8,10,13},{9,0,0,0},{12,0,0,0},{11,12,0,0},{10,11,0,0},{13,14,0,0},{14,15,0,0},
  {15,0,0,0},{8,9,0,0}};
__device__ const int d_Ge[17][4] = {
  {1,0,0,0},{0,1,0,0},{0,1,0,0},{0,1,0,0},{0,1,0,0},{1,0,0,0},{0,0,1,0},{0,1,0,0},
  {0,1,1,1},{1,0,0,0},{1,0,0,0},{1,0,0,0},{0,0,0,0},{0,1,0,0},{0,1,0,0},
  {0,0,0,0},{0,0,0,0}};

// ---------------- K1a: per (b,j,chunk) partial softmax stats ----------------
__global__ __launch_bounds__(256) void k1a(
    const float* __restrict__ x, const float* __restrict__ w_att,
    float* __restrict__ pmax, float* __restrict__ psum)
{
  __shared__ float red[8];
  const int tid = threadIdx.x, lane = tid & 63, wid = tid >> 6;
  const int j = blockIdx.x, b = blockIdx.y, ck = blockIdx.z;
  const int nb = ck * 432;
  float wa[8];
#pragma unroll
  for (int c = 0; c < 8; c++) wa[c] = w_att[j * 8 + c];
  const float* xb = x + (size_t)(b * NC + j * 8) * NSP;
  const int n0 = nb + tid, n1 = nb + tid + 256;
  const bool v1 = tid < 176;
  float s0 = 0.f, s1 = 0.f;
#pragma unroll
  for (int c = 0; c < 8; c++) s0 = fmaf(wa[c], xb[c * NSP + n0], s0);
  if (v1) {
#pragma unroll
    for (int c = 0; c < 8; c++) s1 = fmaf(wa[c], xb[c * NSP + n1], s1);
  }
  float lmax = fmaxf(s0, v1 ? s1 : -3.4e38f);
#pragma unroll
  for (int off = 32; off >= 1; off >>= 1) lmax = fmaxf(lmax, __shfl_xor(lmax, off));
  if (lane == 0) red[wid] = lmax;
  __syncthreads();
  const float M = fmaxf(fmaxf(red[0], red[1]), fmaxf(red[2], red[3]));
  float lsum = __expf(s0 - M) + (v1 ? __expf(s1 - M) : 0.f);
#pragma unroll
  for (int off = 32; off >= 1; off >>= 1) lsum += __shfl_xor(lsum, off);
  if (lane == 0) red[4 + wid] = lsum;
  __syncthreads();
  if (tid == 0) {
    int r4 = (b * NJ + j) * 4 + ck;
    pmax[r4] = M;
    psum[r4] = red[4] + red[5] + red[6] + red[7];
  }
}

// ---------------- K1c: normalize, weighted(bf16), shared partials ----------------
__global__ __launch_bounds__(256) void k1c(
    const float* __restrict__ x, const float* __restrict__ w_pi, const float* __restrict__ w_att,
    const float* __restrict__ pmax, const float* __restrict__ psum,
    float* __restrict__ A_out, short* __restrict__ A_bf,
    short* __restrict__ weighted_bf, float* __restrict__ shpart)
{
  __shared__ float wpis[64];
  __shared__ float shred[4][8];
  const int tid = threadIdx.x, lane = tid & 63, wid = tid >> 6;
  const int j = blockIdx.x, b = blockIdx.y, ck = blockIdx.z;
  const int nb = ck * 432;
  if (tid < 64) wpis[tid] = w_pi[j * 64 + tid];
  float wa[8];
#pragma unroll
  for (int c = 0; c < 8; c++) wa[c] = w_att[j * 8 + c];
  const int r4 = (b * NJ + j) * 4;
  float pm0 = pmax[r4], pm1 = pmax[r4+1], pm2 = pmax[r4+2], pm3 = pmax[r4+3];
  float M = fmaxf(fmaxf(pm0, pm1), fmaxf(pm2, pm3));
  float S = psum[r4] * __expf(pm0 - M) + psum[r4+1] * __expf(pm1 - M)
          + psum[r4+2] * __expf(pm2 - M) + psum[r4+3] * __expf(pm3 - M);
  const float inv = 1.0f / S;
  __syncthreads();
  const float* xb = x + (size_t)(b * NC + j * 8) * NSP;
  const int aoff = (b * NJ + j) * NSP;
  float sh[8];
#pragma unroll
  for (int o = 0; o < 8; o++) sh[o] = 0.f;
#pragma unroll
  for (int i = 0; i < 2; ++i) {
    int n = nb + tid + 256 * i;
    if (i == 0 || tid < 176) {
      float s = 0.f;
      float xv[8];
#pragma unroll
      for (int c = 0; c < 8; c++) xv[c] = xb[c * NSP + n];
#pragma unroll
      for (int c = 0; c < 8; c++) s = fmaf(wa[c], xv[c], s);
      float a = __expf(s - M) * inv;
      A_out[aoff + n] = a;
      A_bf[aoff + n] = f2bf(a);
#pragma unroll
      for (int o = 0; o < 8; o++) {
        float pi = 0.f;
#pragma unroll
        for (int c = 0; c < 8; c++) pi = fmaf(wpis[o * 8 + c], xv[c], pi);
        float w = pi * a;
        weighted_bf[(size_t)((b * NJ + j) * 8 + o) * NSP + n] = f2bf(w);
        sh[o] += w;
      }
    }
  }
#pragma unroll
  for (int o = 0; o < 8; o++) {
    float v = sh[o];
#pragma unroll
    for (int off = 32; off >= 1; off >>= 1) v += __shfl_xor(v, off);
    if (lane == 0) shred[wid][o] = v;
  }
  __syncthreads();
  if (tid < 8)
    shpart[((b * NJ + j) * 8 + tid) * 4 + ck] =
        shred[0][tid] + shred[1][tid] + shred[2][tid] + shred[3][tid];
}

// ---------------- K2: BM=32 rolled-loop reg-resident MFMA GEMM ----------------
__global__ __launch_bounds__(256, 3) void k2(
    const float* __restrict__ limb_mean, const float* __restrict__ limb_std,
    const short* __restrict__ wbf, float* __restrict__ feat)
{
  const float SPf = 2500.0f / 11.0f;
  const float LOG2E = 1.4426950408889634f;
  __shared__ short lut[364];
  __shared__ float den_s[16 * 32];
  __shared__ __attribute__((aligned(16))) float scratch[32 * SST];  // 18944 B

  const int tid = threadIdx.x;
  const int l = blockIdx.y;
  const int m0 = blockIdx.x * 32;
  const int lane = tid & 63, wid = tid >> 6;
  const int lrow = lane & 15;
  const int lk8 = (lane >> 4) * 8;
  const int wrow = (wid & 1) * 16;   // m-strip owned by this wave
  const int kkb = (wid >> 1) * 32;   // K-half (n-offset within 64-tile)
  const int nbl = kkb + lk8;

  const float mean = limb_mean[l];
  const float sd = limb_std[l];
  const float invd2 = LOG2E / (20.0f * sd * sd + 0.1f);

  for (int i = tid; i < 364; i += 256) {
    float t = fmaf(SPf, sqrtf((float)i), -mean);
    lut[i] = f2bf(exp2f(-(t * invd2) * t));
  }
  __syncthreads();

  // per-lane m coordinates (1 m-row, fixed for whole kernel)
  const int mA = m0 + wrow + lrow;
  const int msx0 = mA / 144, r0_ = mA - msx0 * 144, msy0 = r0_ / 12, msz0 = r0_ - msy0 * 12;

  // per-lane global base pointers for the 9 B-fragment rows
  const int ja = d_CA[l], jb = d_CB[l];
  const short* gpc[9];
#pragma unroll
  for (int c = 0; c < 9; ++c) {
    int row = c * 16 + lrow;
    int bb = row / 18, s = row - bb * 18;
    int off;
    if (s < 8)        off = ((bb * NJ + ja) * CPJ + s) * NSP;
    else if (s < 16)  off = ((bb * NJ + jb) * CPJ + (s - 8)) * NSP;
    else if (s == 16) off = WA_OFF + (bb * NJ + ja) * NSP;
    else              off = WA_OFF + (bb * NJ + jb) * NSP;
    gpc[c] = wbf + off + nbl;
  }

  auto genA = [&](int n0) {
    short8 af;
#pragma unroll
    for (int i = 0; i < 8; ++i) {
      int n = n0 + nbl + i;
      int nx = n / 144, r = n - nx * 144, ny = r / 12, nz = r - ny * 12;
      int dx = msx0 - nx, dy = msy0 - ny, dz = msz0 - nz;
      af[i] = lut[dx * dx + dy * dy + dz * dz];
    }
    return af;
  };

  f32x4 acc[9];
#pragma unroll
  for (int c = 0; c < 9; c++) acc[c] = (f32x4){0,0,0,0};

  // prologue: tile 0 fragments
  short8 aC = genA(0);
  short8 bC[9];
#pragma unroll
  for (int c = 0; c < 9; ++c) bC[c] = *reinterpret_cast<const short8*>(gpc[c]);

#pragma unroll 2
  for (int nt = 0; nt < 27; ++nt) {
    short8 aN;
    short8 bN[9];
    if (nt < 26) {
      const int n0n = (nt + 1) * 64;
#pragma unroll
      for (int c = 0; c < 9; ++c) bN[c] = *reinterpret_cast<const short8*>(gpc[c] + n0n);
      aN = genA(n0n);
    }
#pragma unroll
    for (int c = 0; c < 9; ++c)
      acc[c] = __builtin_amdgcn_mfma_f32_16x16x32_bf16(aC, bC[c], acc[c], 0, 0, 0);
    if (nt < 26) {
      aC = aN;
#pragma unroll
      for (int c = 0; c < 9; ++c) bC[c] = bN[c];
    }
  }

  // ---- epilogue: K-split reduce (waves 2,3 -> scratch; waves 0,1 add) ----
  const int rbase = 4 * (lane >> 4);
  if (wid >= 2) {
#pragma unroll
    for (int c = 0; c < 9; ++c) {
#pragma unroll
      for (int r = 0; r < 4; ++r)
        scratch[(wrow + rbase + r) * SST + c * 16 + lrow] = acc[c][r];
    }
  }
  __syncthreads();
  if (wid < 2) {
#pragma unroll
    for (int c = 0; c < 9; ++c) {
#pragma unroll
      for (int r = 0; r < 4; ++r)
        acc[c][r] += scratch[(wrow + rbase + r) * SST + c * 16 + lrow];
    }
#pragma unroll
    for (int c = 0; c < 9; ++c) {
      int col = c * 16 + lrow;
      int b = col / 18, s = col - b * 18;
      if (s >= 16) {
#pragma unroll
        for (int r = 0; r < 4; ++r)
          den_s[(b * 2 + (s - 16)) * 32 + wrow + rbase + r] = 1.0f / acc[c][r];
      }
    }
  }
  __syncthreads();
  if (wid < 2) {
#pragma unroll
    for (int c = 0; c < 9; ++c) {
      int col = c * 16 + lrow;
      int b = col / 18, s = col - b * 18;
      if (s < 16) {
        int e = s >> 3, ch = s & 7;
        size_t obase = ((size_t)(b * 16 + l) * 2 + e) * (NSP * 8) + ch;
#pragma unroll
        for (int r = 0; r < 4; ++r) {
          int m1 = wrow + rbase + r;
          feat[obase + (size_t)(m0 + m1) * 8] = acc[c][r] * den_s[(b * 2 + e) * 32 + m1];
        }
      }
    }
  }
}

// ---------------- K3: final conv with group substitution + x_pi add ----------------
__global__ __launch_bounds__(256) void k3(
    const float* __restrict__ x, const float* __restrict__ w_pi, const float* __restrict__ w_conv,
    const float* __restrict__ shpart, const float* __restrict__ feat,
    float* __restrict__ out)
{
  __shared__ float wcs[8 * NC];
  __shared__ float wpis[64];
  __shared__ float sh[NC];
  __shared__ float cts[8];
  const int tid = threadIdx.x;
  const int j0 = blockIdx.x, b = blockIdx.y;
  const int n = blockIdx.z * 256 + tid;
  for (int i = tid; i < 8 * NC; i += 256) wcs[i] = w_conv[j0 * 8 * NC + i];
  if (tid < 64) wpis[tid] = w_pi[j0 * 64 + tid];
  if (tid < NC) {
    const float* p = shpart + ((b * NJ) * 8 + tid) * 4;  // channel tid of batch b
    sh[tid] = p[0] + p[1] + p[2] + p[3];
  }
  __syncthreads();
  const int cnt = d_Gcnt[j0];
  if (tid < 8) {
    float v = 0.f;
    for (int c = 0; c < NC; c++) v = fmaf(wcs[tid * NC + c], sh[c], v);
    for (int g = 0; g < cnt; ++g) {
      int j1 = d_Gj1[j0][g];
      for (int cc = 0; cc < 8; ++cc) v -= wcs[tid * NC + j1 * 8 + cc] * sh[j1 * 8 + cc];
    }
    cts[tid] = v;
  }
  __syncthreads();
  if (n < NSP) {
    const float* xb = x + (size_t)(b * NC + j0 * 8) * NSP;
    float xv[8];
#pragma unroll
    for (int c = 0; c < 8; c++) xv[c] = xb[c * NSP + n];
    float o8[8];
#pragma unroll
    for (int o = 0; o < 8; o++) {
      float pi = 0.f;
#pragma unroll
      for (int c = 0; c < 8; c++) pi = fmaf(wpis[o * 8 + c], xv[c], pi);
      o8[o] = cts[o] + pi;
    }
    for (int g = 0; g < cnt; ++g) {
      int j1 = d_Gj1[j0][g], lim = d_Glim[j0][g], e = d_Ge[j0][g];
      const float* fb = feat + ((size_t)(b * 16 + lim) * 2 + e) * (NSP * 8) + (size_t)n * 8;
      float4 flo = *reinterpret_cast<const float4*>(fb);
      float4 fhi = *reinterpret_cast<const float4*>(fb + 4);
      float fv[8] = {flo.x, flo.y, flo.z, flo.w, fhi.x, fhi.y, fhi.z, fhi.w};
#pragma unroll
      for (int o = 0; o < 8; o++)
#pragma unroll
        for (int cc = 0; cc < 8; cc++)
          o8[o] = fmaf(wcs[o * NC + j1 * 8 + cc], fv[cc], o8[o]);
    }
#pragma unroll
    for (int o = 0; o < 8; o++)
      out[(size_t)(b * NC + j0 * 8 + o) * NSP + n] = o8[o];
  }
}

extern "C" void kernel_launch(void* const* d_in, const int* in_sizes, int n_in,
                              void* d_out, int out_size, void* d_ws, size_t ws_size,
                              hipStream_t stream) {
  const float* x         = (const float*)d_in[0];
  const float* w_pi      = (const float*)d_in[1];
  const float* w_att     = (const float*)d_in[2];
  const float* w_conv    = (const float*)d_in[3];
  const float* limb_mean = (const float*)d_in[4];
  const float* limb_std  = (const float*)d_in[5];

  float* out   = (float*)d_out;
  float* A_out = out + 1880064;            // out(8*136*1728) then A(8*17*1728)

  short* W_bf    = (short*)d_ws;                          // weighted(1,880,064) + A(235,008) bf16
  char*  base    = (char*)d_ws + 4230144;
  float* W_pmax  = (float*)base;                          // 544
  float* W_psum  = (float*)(base + 2176);                 // 544
  float* W_shp   = (float*)(base + 4352);                 // 4352
  float* W_feat  = (float*)(base + 21760);                // 3,538,944 floats [b][l][e][n][ch]

  hipLaunchKernelGGL(k1a, dim3(NJ, NBATCH, 4), dim3(256), 0, stream,
                     x, w_att, W_pmax, W_psum);
  hipLaunchKernelGGL(k1c, dim3(NJ, NBATCH, 4), dim3(256), 0, stream,
                     x, w_pi, w_att, W_pmax, W_psum, A_out, W_bf + WA_OFF, W_bf, W_shp);
  hipLaunchKernelGGL(k2, dim3(54, 16), dim3(256), 0, stream,
                     limb_mean, limb_std, W_bf, W_feat);
  hipLaunchKernelGGL(k3, dim3(NJ, NBATCH, 7), dim3(256), 0, stream,
                     x, w_pi, w_conv, W_shp, W_feat, out);
}

// Round 12
// 127.988 us; speedup vs baseline: 1.5656x; 1.5656x over previous
//
#include <hip/hip_runtime.h>
#include <math.h>

#define NJ 17
#define CPJ 8
#define NBATCH 8
#define NSP 1728
#define NC 136
#define WA_OFF 1880064  // element offset of bf16 A copy inside bf16 ws region
#define SST 148         // epilogue scratch stride (floats)

typedef short short8 __attribute__((ext_vector_type(8)));
typedef float f32x4 __attribute__((ext_vector_type(4)));

__device__ __forceinline__ short f2bf(float f) {
  unsigned u = __builtin_bit_cast(unsigned, f);
  u += 0x7FFFu + ((u >> 16) & 1u);   // RNE
  return (short)(u >> 16);
}

__device__ const int d_CA[16] = {0,1,2,5,4,3,6,7,8,9,8,11,10,8,13,14};
__device__ const int d_CB[16] = {1,2,6,4,3,6,7,8,16,16,12,12,11,13,14,15};
__device__ const int d_Gcnt[17] = {1,2,2,2,2,1,3,2,4,1,1,2,2,2,2,1,2};
__device__ const int d_Gj1[17][4] = {
  {1,0,0,0},{0,2,0,0},{1,6,0,0},{4,6,0,0},{5,3,0,0},{4,0,0,0},{2,3,7,0},{6,8,0,0},
  {7,16,12,13},{16,0,0,0},{11,0,0,0},{12,10,0,0},{8,11,0,0},{8,14,0,0},{13,15,0,0},
  {14,0,0,0},{8,9,0,0}};
__device__ const int d_Glim[17][4] = {
  {0,0,0,0},{0,1,0,0},{1,2,0,0},{4,5,0,0},{3,4,0,0},{3,0,0,0},{2,5,6,0},{6,7,0,0},
  {7,8,10,13},{9,0,0,0},{12,0,0,0},{11,12,0,0},{10,11,0,0},{13,14,0,0},{14,15,0,0},
  {15,0,0,0},{8,9,0,0}};
__device__ const int d_Ge[17][4] = {
  {1,0,0,0},{0,1,0,0},{0,1,0,0},{0,1,0,0},{0,1,0,0},{1,0,0,0},{0,0,1,0},{0,1,0,0},
  {0,1,1,1},{1,0,0,0},{1,0,0,0},{1,0,0,0},{0,0,0,0},{0,1,0,0},{0,1,0,0},
  {0,0,0,0},{0,0,0,0}};

// ---------------- K1a: per (b,j,chunk) partial softmax stats ----------------
__global__ __launch_bounds__(256) void k1a(
    const float* __restrict__ x, const float* __restrict__ w_att,
    float* __restrict__ pmax, float* __restrict__ psum)
{
  __shared__ float red[8];
  const int tid = threadIdx.x, lane = tid & 63, wid = tid >> 6;
  const int j = blockIdx.x, b = blockIdx.y, ck = blockIdx.z;
  const int nb = ck * 432;
  float wa[8];
#pragma unroll
  for (int c = 0; c < 8; c++) wa[c] = w_att[j * 8 + c];
  const float* xb = x + (size_t)(b * NC + j * 8) * NSP;
  const int n0 = nb + tid, n1 = nb + tid + 256;
  const bool v1 = tid < 176;
  float s0 = 0.f, s1 = 0.f;
#pragma unroll
  for (int c = 0; c < 8; c++) s0 = fmaf(wa[c], xb[c * NSP + n0], s0);
  if (v1) {
#pragma unroll
    for (int c = 0; c < 8; c++) s1 = fmaf(wa[c], xb[c * NSP + n1], s1);
  }
  float lmax = fmaxf(s0, v1 ? s1 : -3.4e38f);
#pragma unroll
  for (int off = 32; off >= 1; off >>= 1) lmax = fmaxf(lmax, __shfl_xor(lmax, off));
  if (lane == 0) red[wid] = lmax;
  __syncthreads();
  const float M = fmaxf(fmaxf(red[0], red[1]), fmaxf(red[2], red[3]));
  float lsum = __expf(s0 - M) + (v1 ? __expf(s1 - M) : 0.f);
#pragma unroll
  for (int off = 32; off >= 1; off >>= 1) lsum += __shfl_xor(lsum, off);
  if (lane == 0) red[4 + wid] = lsum;
  __syncthreads();
  if (tid == 0) {
    int r4 = (b * NJ + j) * 4 + ck;
    pmax[r4] = M;
    psum[r4] = red[4] + red[5] + red[6] + red[7];
  }
}

// ---------------- K1c: normalize, weighted(bf16), shared partials ----------------
__global__ __launch_bounds__(256) void k1c(
    const float* __restrict__ x, const float* __restrict__ w_pi, const float* __restrict__ w_att,
    const float* __restrict__ pmax, const float* __restrict__ psum,
    float* __restrict__ A_out, short* __restrict__ A_bf,
    short* __restrict__ weighted_bf, float* __restrict__ shpart)
{
  __shared__ float wpis[64];
  __shared__ float shred[4][8];
  const int tid = threadIdx.x, lane = tid & 63, wid = tid >> 6;
  const int j = blockIdx.x, b = blockIdx.y, ck = blockIdx.z;
  const int nb = ck * 432;
  if (tid < 64) wpis[tid] = w_pi[j * 64 + tid];
  float wa[8];
#pragma unroll
  for (int c = 0; c < 8; c++) wa[c] = w_att[j * 8 + c];
  const int r4 = (b * NJ + j) * 4;
  float pm0 = pmax[r4], pm1 = pmax[r4+1], pm2 = pmax[r4+2], pm3 = pmax[r4+3];
  float M = fmaxf(fmaxf(pm0, pm1), fmaxf(pm2, pm3));
  float S = psum[r4] * __expf(pm0 - M) + psum[r4+1] * __expf(pm1 - M)
          + psum[r4+2] * __expf(pm2 - M) + psum[r4+3] * __expf(pm3 - M);
  const float inv = 1.0f / S;
  __syncthreads();
  const float* xb = x + (size_t)(b * NC + j * 8) * NSP;
  const int aoff = (b * NJ + j) * NSP;
  float sh[8];
#pragma unroll
  for (int o = 0; o < 8; o++) sh[o] = 0.f;
#pragma unroll
  for (int i = 0; i < 2; ++i) {
    int n = nb + tid + 256 * i;
    if (i == 0 || tid < 176) {
      float s = 0.f;
      float xv[8];
#pragma unroll
      for (int c = 0; c < 8; c++) xv[c] = xb[c * NSP + n];
#pragma unroll
      for (int c = 0; c < 8; c++) s = fmaf(wa[c], xv[c], s);
      float a = __expf(s - M) * inv;
      A_out[aoff + n] = a;
      A_bf[aoff + n] = f2bf(a);
#pragma unroll
      for (int o = 0; o < 8; o++) {
        float pi = 0.f;
#pragma unroll
        for (int c = 0; c < 8; c++) pi = fmaf(wpis[o * 8 + c], xv[c], pi);
        float w = pi * a;
        weighted_bf[(size_t)((b * NJ + j) * 8 + o) * NSP + n] = f2bf(w);
        sh[o] += w;
      }
    }
  }
#pragma unroll
  for (int o = 0; o < 8; o++) {
    float v = sh[o];
#pragma unroll
    for (int off = 32; off >= 1; off >>= 1) v += __shfl_xor(v, off);
    if (lane == 0) shred[wid][o] = v;
  }
  __syncthreads();
  if (tid < 8)
    shpart[((b * NJ + j) * 8 + tid) * 4 + ck] =
        shred[0][tid] + shred[1][tid] + shred[2][tid] + shred[3][tid];
}

// ---------------- K1r: repack weighted+A into limb-major tiled layout ----------------
// Wl[l][nt][row][32] bf16, nt = n/32, row = b*18 + s (s: 8 wA, 8 wB, aA, aB)
__global__ __launch_bounds__(256) void k1r(
    const short* __restrict__ wbf, short* __restrict__ Wl)
{
  __shared__ int rowbase[144];
  const int tid = threadIdx.x;
  const int l = blockIdx.y;
  const int n0 = blockIdx.x * 64;
  if (tid < 144) {
    int b = tid / 18, s = tid - b * 18;
    int ja = d_CA[l], jb = d_CB[l];
    int off;
    if (s < 8)        off = ((b * NJ + ja) * CPJ + s) * NSP;
    else if (s < 16)  off = ((b * NJ + jb) * CPJ + (s - 8)) * NSP;
    else if (s == 16) off = WA_OFF + (b * NJ + ja) * NSP;
    else              off = WA_OFF + (b * NJ + jb) * NSP;
    rowbase[tid] = off;
  }
  __syncthreads();
  // 144 rows x 8 chunks of 8 elems = 1152 chunks
#pragma unroll
  for (int it = 0; it < 5; ++it) {
    int idx = tid + 256 * it;
    if (idx < 1152) {
      int row = idx >> 3, c8 = idx & 7;
      int4 v = *reinterpret_cast<const int4*>(wbf + rowbase[row] + n0 + c8 * 8);
      int nt = (n0 >> 5) + (c8 >> 2);
      int koff = (c8 & 3) * 8;
      *reinterpret_cast<int4*>(&Wl[(((size_t)l * 54 + nt) * 144 + row) * 32 + koff]) = v;
    }
  }
}

// ---------------- K2: BM=64, coalesced B loads from Wl, LUT P-gen, MFMA ----------------
__global__ __launch_bounds__(256, 2) void k2(
    const float* __restrict__ limb_mean, const float* __restrict__ limb_std,
    const short* __restrict__ Wl, float* __restrict__ feat)
{
  const float SPf = 2500.0f / 11.0f;
  const float LOG2E = 1.4426950408889634f;
  __shared__ short lut[364];
  __shared__ float den_s[16 * 64];
  __shared__ __attribute__((aligned(16))) float scratch[64 * SST];  // 37888 B

  const int tid = threadIdx.x;
  const int l = blockIdx.y;
  const int m0 = blockIdx.x * 64;
  const int lane = tid & 63, wid = tid >> 6;
  const int lrow = lane & 15;
  const int lk8 = (lane >> 4) * 8;
  const int wrow = (wid & 1) * 32;   // m-strip pair owned by this wave
  const int p = wid >> 1;            // tile parity (K-split)

  const float mean = limb_mean[l];
  const float sd = limb_std[l];
  const float invd2 = LOG2E / (20.0f * sd * sd + 0.1f);

  for (int i = tid; i < 364; i += 256) {
    float t = fmaf(SPf, sqrtf((float)i), -mean);
    lut[i] = f2bf(exp2f(-(t * invd2) * t));
  }
  __syncthreads();

  // per-lane m coordinates (2 m-rows, fixed for whole kernel)
  const int mA = m0 + wrow + lrow, mB = mA + 16;
  const int msx0 = mA / 144, r0_ = mA - msx0 * 144, msy0 = r0_ / 12, msz0 = r0_ - msy0 * 12;
  const int msx1 = mB / 144, r1_ = mB - msx1 * 144, msy1 = r1_ / 12, msz1 = r1_ - msy1 * 12;

  // coalesced B base: lanes 0-63 cover rows lrow(16) x k-groups lk8(4) = contiguous 1KB/instr
  const short* gp0 = Wl + ((size_t)(l * 54 + p) * 144 + lrow) * 32 + lk8;

  struct AF { short8 a0, a1; };
  auto genA = [&](int n0) {
    AF af;
#pragma unroll
    for (int i = 0; i < 8; ++i) {
      int n = n0 + lk8 + i;
      int nx = n / 144, r = n - nx * 144, ny = r / 12, nz = r - ny * 12;
      int dx0 = msx0 - nx, dy0 = msy0 - ny, dz0 = msz0 - nz;
      af.a0[i] = lut[dx0 * dx0 + dy0 * dy0 + dz0 * dz0];
      int dx1 = msx1 - nx, dy1 = msy1 - ny, dz1 = msz1 - nz;
      af.a1[i] = lut[dx1 * dx1 + dy1 * dy1 + dz1 * dz1];
    }
    return af;
  };

  f32x4 acc0[9], acc1[9];
#pragma unroll
  for (int c = 0; c < 9; c++) { acc0[c] = (f32x4){0,0,0,0}; acc1[c] = (f32x4){0,0,0,0}; }

  // prologue: this wave's tile 0 (global tile index p)
  AF aC = genA(p * 32);
  short8 bC[9];
#pragma unroll
  for (int c = 0; c < 9; ++c) bC[c] = *reinterpret_cast<const short8*>(gp0 + c * 512);

#pragma unroll 2
  for (int t = 0; t < 27; ++t) {
    AF aN;
    short8 bN[9];
    if (t < 26) {
      const int toff = (t + 1) * 9216;   // 2 tiles * 144 rows * 32
#pragma unroll
      for (int c = 0; c < 9; ++c)
        bN[c] = *reinterpret_cast<const short8*>(gp0 + c * 512 + toff);
      aN = genA((2 * (t + 1) + p) * 32);
    }
#pragma unroll
    for (int c = 0; c < 9; ++c) {
      acc0[c] = __builtin_amdgcn_mfma_f32_16x16x32_bf16(aC.a0, bC[c], acc0[c], 0, 0, 0);
      acc1[c] = __builtin_amdgcn_mfma_f32_16x16x32_bf16(aC.a1, bC[c], acc1[c], 0, 0, 0);
    }
    if (t < 26) {
      aC = aN;
#pragma unroll
      for (int c = 0; c < 9; ++c) bC[c] = bN[c];
    }
  }

  // ---- epilogue: K-parity reduce (waves 2,3 -> scratch; waves 0,1 add) ----
  const int rbase = 4 * (lane >> 4);
  if (wid >= 2) {
#pragma unroll
    for (int c = 0; c < 9; ++c) {
#pragma unroll
      for (int r = 0; r < 4; ++r) {
        scratch[(wrow + rbase + r) * SST + c * 16 + lrow] = acc0[c][r];
        scratch[(wrow + 16 + rbase + r) * SST + c * 16 + lrow] = acc1[c][r];
      }
    }
  }
  __syncthreads();
  if (wid < 2) {
#pragma unroll
    for (int c = 0; c < 9; ++c) {
#pragma unroll
      for (int r = 0; r < 4; ++r) {
        acc0[c][r] += scratch[(wrow + rbase + r) * SST + c * 16 + lrow];
        acc1[c][r] += scratch[(wrow + 16 + rbase + r) * SST + c * 16 + lrow];
      }
    }
#pragma unroll
    for (int c = 0; c < 9; ++c) {
      int col = c * 16 + lrow;
      int b = col / 18, s = col - b * 18;
      if (s >= 16) {
#pragma unroll
        for (int r = 0; r < 4; ++r) {
          den_s[(b * 2 + (s - 16)) * 64 + wrow + rbase + r] = 1.0f / acc0[c][r];
          den_s[(b * 2 + (s - 16)) * 64 + wrow + 16 + rbase + r] = 1.0f / acc1[c][r];
        }
      }
    }
  }
  __syncthreads();
  if (wid < 2) {
#pragma unroll
    for (int c = 0; c < 9; ++c) {
      int col = c * 16 + lrow;
      int b = col / 18, s = col - b * 18;
      if (s < 16) {
        int e = s >> 3, ch = s & 7;
        size_t obase = ((size_t)(b * 16 + l) * 2 + e) * (NSP * 8) + ch;
#pragma unroll
        for (int r = 0; r < 4; ++r) {
          int m1 = wrow + rbase + r, m2 = wrow + 16 + rbase + r;
          feat[obase + (size_t)(m0 + m1) * 8] = acc0[c][r] * den_s[(b * 2 + e) * 64 + m1];
          feat[obase + (size_t)(m0 + m2) * 8] = acc1[c][r] * den_s[(b * 2 + e) * 64 + m2];
        }
      }
    }
  }
}

// ---------------- K3: final conv with group substitution + x_pi add ----------------
__global__ __launch_bounds__(256) void k3(
    const float* __restrict__ x, const float* __restrict__ w_pi, const float* __restrict__ w_conv,
    const float* __restrict__ shpart, const float* __restrict__ feat,
    float* __restrict__ out)
{
  __shared__ float wcs[8 * NC];
  __shared__ float wpis[64];
  __shared__ float sh[NC];
  __shared__ float cts[8];
  const int tid = threadIdx.x;
  const int j0 = blockIdx.x, b = blockIdx.y;
  const int n = blockIdx.z * 256 + tid;
  for (int i = tid; i < 8 * NC; i += 256) wcs[i] = w_conv[j0 * 8 * NC + i];
  if (tid < 64) wpis[tid] = w_pi[j0 * 64 + tid];
  if (tid < NC) {
    const float* p = shpart + ((b * NJ) * 8 + tid) * 4;  // channel tid of batch b
    sh[tid] = p[0] + p[1] + p[2] + p[3];
  }
  __syncthreads();
  const int cnt = d_Gcnt[j0];
  if (tid < 8) {
    float v = 0.f;
    for (int c = 0; c < NC; c++) v = fmaf(wcs[tid * NC + c], sh[c], v);
    for (int g = 0; g < cnt; ++g) {
      int j1 = d_Gj1[j0][g];
      for (int cc = 0; cc < 8; ++cc) v -= wcs[tid * NC + j1 * 8 + cc] * sh[j1 * 8 + cc];
    }
    cts[tid] = v;
  }
  __syncthreads();
  if (n < NSP) {
    const float* xb = x + (size_t)(b * NC + j0 * 8) * NSP;
    float xv[8];
#pragma unroll
    for (int c = 0; c < 8; c++) xv[c] = xb[c * NSP + n];
    float o8[8];
#pragma unroll
    for (int o = 0; o < 8; o++) {
      float pi = 0.f;
#pragma unroll
      for (int c = 0; c < 8; c++) pi = fmaf(wpis[o * 8 + c], xv[c], pi);
      o8[o] = cts[o] + pi;
    }
    for (int g = 0; g < cnt; ++g) {
      int j1 = d_Gj1[j0][g], lim = d_Glim[j0][g], e = d_Ge[j0][g];
      const float* fb = feat + ((size_t)(b * 16 + lim) * 2 + e) * (NSP * 8) + (size_t)n * 8;
      float4 flo = *reinterpret_cast<const float4*>(fb);
      float4 fhi = *reinterpret_cast<const float4*>(fb + 4);
      float fv[8] = {flo.x, flo.y, flo.z, flo.w, fhi.x, fhi.y, fhi.z, fhi.w};
#pragma unroll
      for (int o = 0; o < 8; o++)
#pragma unroll
        for (int cc = 0; cc < 8; cc++)
          o8[o] = fmaf(wcs[o * NC + j1 * 8 + cc], fv[cc], o8[o]);
    }
#pragma unroll
    for (int o = 0; o < 8; o++)
      out[(size_t)(b * NC + j0 * 8 + o) * NSP + n] = o8[o];
  }
}

extern "C" void kernel_launch(void* const* d_in, const int* in_sizes, int n_in,
                              void* d_out, int out_size, void* d_ws, size_t ws_size,
                              hipStream_t stream) {
  const float* x         = (const float*)d_in[0];
  const float* w_pi      = (const float*)d_in[1];
  const float* w_att     = (const float*)d_in[2];
  const float* w_conv    = (const float*)d_in[3];
  const float* limb_mean = (const float*)d_in[4];
  const float* limb_std  = (const float*)d_in[5];

  float* out   = (float*)d_out;
  float* A_out = out + 1880064;            // out(8*136*1728) then A(8*17*1728)

  short* W_bf    = (short*)d_ws;                          // weighted(1,880,064) + A(235,008) bf16
  char*  base    = (char*)d_ws + 4230144;
  float* W_pmax  = (float*)base;                          // 544
  float* W_psum  = (float*)(base + 2176);                 // 544
  float* W_shp   = (float*)(base + 4352);                 // 4352
  float* W_feat  = (float*)(base + 21760);                // 3,538,944 floats [b][l][e][n][ch]
  short* W_l     = (short*)(base + 21760 + 14155776);     // 16*54*144*32 bf16 = 7.96 MB

  hipLaunchKernelGGL(k1a, dim3(NJ, NBATCH, 4), dim3(256), 0, stream,
                     x, w_att, W_pmax, W_psum);
  hipLaunchKernelGGL(k1c, dim3(NJ, NBATCH, 4), dim3(256), 0, stream,
                     x, w_pi, w_att, W_pmax, W_psum, A_out, W_bf + WA_OFF, W_bf, W_shp);
  hipLaunchKernelGGL(k1r, dim3(27, 16), dim3(256), 0, stream,
                     W_bf, W_l);
  hipLaunchKernelGGL(k2, dim3(27, 16), dim3(256), 0, stream,
                     limb_mean, limb_std, W_l, W_feat);
  hipLaunchKernelGGL(k3, dim3(NJ, NBATCH, 7), dim3(256), 0, stream,
                     x, w_pi, w_conv, W_shp, W_feat, out);
}